// Round 1
// baseline (9250.704 us; speedup 1.0000x reference)
//
#include <hip/hip_runtime.h>
#include <hip/hip_bf16.h>
#include <math.h>

// ---------------- problem constants ----------------
#define BB 64
#define CC 3
#define HH 256
#define WW 256
#define PP 16
#define DD 1024
#define DEPTH 10
#define HEADS 2
#define DHD 64
#define MLPD 256
#define INNER 128          // HEADS*DHD
#define NCLS 16
#define NT 288             // tokens: 16 cls + 256 patch + 16 cls
#define PDIM 768           // C*P*P
#define SIDE_ 16
#define HPn 16
#define WPn 18
#define SCALE_ 0.125f

// ---------------- helpers ----------------
__device__ __forceinline__ float gelu_f(float x) {
    return 0.5f * x * (1.0f + erff(x * 0.70710678118654752f));
}

__device__ __forceinline__ float block_sum_1024(float v, float* red) {
    // 256 threads, 4 waves. Returns total to all threads.
    #pragma unroll
    for (int off = 32; off; off >>= 1) v += __shfl_xor(v, off);
    __syncthreads();                       // protect previous use of red
    if ((threadIdx.x & 63) == 0) red[threadIdx.x >> 6] = v;
    __syncthreads();
    return red[0] + red[1] + red[2] + red[3];
}

// ---------------- patch gather ----------------
// Xp[b*256 + hp*16+wp][(py*16+px)*3 + c] = img[b][c][hp*16+py][wp*16+px]
__global__ __launch_bounds__(256)
void build_patches(const float* __restrict__ img, float* __restrict__ Xp) {
    size_t e = (size_t)blockIdx.x * 256 + threadIdx.x;  // 64*256*768
    int pd = (int)(e % 768); size_t r = e / 768;
    int t  = (int)(r % 256); int b = (int)(r / 256);
    int c = pd % 3; int pp = pd / 3; int px = pp & 15, py = pp >> 4;
    int wp = t & 15, hp = t >> 4;
    Xp[e] = img[(((size_t)b * 3 + c) * 256 + hp * 16 + py) * 256 + wp * 16 + px];
}

// ---------------- x assembly: cls | patches | cls, + pos_emb ----------------
__global__ __launch_bounds__(256)
void assemble_x(const float* __restrict__ pe_out, const float* __restrict__ clbuf,
                const float* __restrict__ pos, float* __restrict__ X) {
    size_t e = (size_t)blockIdx.x * 256 + threadIdx.x;   // 64*288*1024
    int d = (int)(e & 1023); size_t r = e >> 10;
    int t = (int)(r % NT); int b = (int)(r / NT);
    float v;
    if (t < 16)       v = clbuf[t * 1024 + d];
    else if (t < 272) v = pe_out[((size_t)b * 256 + (t - 16)) * 1024 + d];
    else              v = clbuf[(16 + t - 272) * 1024 + d];
    X[e] = v + pos[t * 1024 + d];
}

// ---------------- LayerNorm (one block per token, D=1024) ----------------
__global__ __launch_bounds__(256)
void ln_kernel(const float* __restrict__ X, const float* __restrict__ sc,
               const float* __restrict__ bi, float* __restrict__ Y) {
    __shared__ float red[4];
    size_t base = (size_t)blockIdx.x * 1024;
    int tid = threadIdx.x;
    float4 v = *(const float4*)&X[base + tid * 4];
    float s = v.x + v.y + v.z + v.w;
    float mean = block_sum_1024(s, red) * (1.0f / 1024.0f);
    float dx = v.x - mean, dy = v.y - mean, dz = v.z - mean, dw = v.w - mean;
    float sq = dx * dx + dy * dy + dz * dz + dw * dw;
    float var = block_sum_1024(sq, red) * (1.0f / 1024.0f);
    float rs = rsqrtf(var + 1e-5f);
    float4 s4 = *(const float4*)&sc[tid * 4];
    float4 b4 = *(const float4*)&bi[tid * 4];
    float4 o;
    o.x = dx * rs * s4.x + b4.x;
    o.y = dy * rs * s4.y + b4.y;
    o.z = dz * rs * s4.z + b4.z;
    o.w = dw * rs * s4.w + b4.w;
    *(float4*)&Y[base + tid * 4] = o;
}

// ---------------- f32 GEMM: C[M,Nn] = A[M,K] @ W[K,Nn] (+epilogue) ----------
// EPI: 0=none, 1=+bias, 2=+bias+residual(in-place on Cout), 3=gelu(.+bias)
template<int EPI>
__global__ __launch_bounds__(256)
void gemm_f32(const float* __restrict__ A, const float* __restrict__ Wt,
              const float* __restrict__ bias, float* __restrict__ Cout,
              int M, int Nn, int K) {
    __shared__ float As[16][132];   // [k][row], padded
    __shared__ float Bs[16][68];    // [k][col], padded
    const int tid = threadIdx.x;
    const int m0 = blockIdx.y * 128;
    const int n0 = blockIdx.x * 64;
    const int ty = tid >> 4, tx = tid & 15;
    float acc[8][4];
    #pragma unroll
    for (int r = 0; r < 8; r++)
        #pragma unroll
        for (int c = 0; c < 4; c++) acc[r][c] = 0.0f;

    const int af4 = tid & 3;       // which float4 of the 16-wide k-slice
    const int arow0 = tid >> 2;    // 0..63
    const int bcol = tid & 63, brow0 = tid >> 6;

    for (int k0 = 0; k0 < K; k0 += 16) {
        #pragma unroll
        for (int rr = 0; rr < 2; rr++) {
            int row = arow0 + rr * 64;
            int gm = m0 + row;
            float4 v = make_float4(0.f, 0.f, 0.f, 0.f);
            if (gm < M) v = *(const float4*)&A[(size_t)gm * K + k0 + af4 * 4];
            As[af4 * 4 + 0][row] = v.x;
            As[af4 * 4 + 1][row] = v.y;
            As[af4 * 4 + 2][row] = v.z;
            As[af4 * 4 + 3][row] = v.w;
        }
        #pragma unroll
        for (int rr = 0; rr < 4; rr++) {
            int krow = brow0 + rr * 4;
            Bs[krow][bcol] = Wt[(size_t)(k0 + krow) * Nn + n0 + bcol];
        }
        __syncthreads();
        #pragma unroll
        for (int kk = 0; kk < 16; kk++) {
            float4 a0 = *(const float4*)&As[kk][ty * 8];
            float4 a1 = *(const float4*)&As[kk][ty * 8 + 4];
            float4 b0 = *(const float4*)&Bs[kk][tx * 4];
            float ar[8] = {a0.x, a0.y, a0.z, a0.w, a1.x, a1.y, a1.z, a1.w};
            float bc[4] = {b0.x, b0.y, b0.z, b0.w};
            #pragma unroll
            for (int r = 0; r < 8; r++)
                #pragma unroll
                for (int c = 0; c < 4; c++)
                    acc[r][c] = fmaf(ar[r], bc[c], acc[r][c]);
        }
        __syncthreads();
    }
    float4 bv = make_float4(0.f, 0.f, 0.f, 0.f);
    if (EPI >= 1) bv = *(const float4*)&bias[n0 + tx * 4];
    #pragma unroll
    for (int r = 0; r < 8; r++) {
        int gm = m0 + ty * 8 + r;
        if (gm >= M) continue;
        float4 v = make_float4(acc[r][0], acc[r][1], acc[r][2], acc[r][3]);
        if (EPI >= 1) { v.x += bv.x; v.y += bv.y; v.z += bv.z; v.w += bv.w; }
        if (EPI == 3) { v.x = gelu_f(v.x); v.y = gelu_f(v.y); v.z = gelu_f(v.z); v.w = gelu_f(v.w); }
        float* outp = &Cout[(size_t)gm * Nn + n0 + tx * 4];
        if (EPI == 2) {
            float4 rv = *(const float4*)outp;
            v.x += rv.x; v.y += rv.y; v.z += rv.z; v.w += rv.w;
        }
        *(float4*)outp = v;
    }
}

// ---------------- attention (flash-style, f32, QT=KT=32) ----------------
// qkv: (B, NT, 384) with q|k|v each 128 (h*64+d). O: (B, NT, 128)
__global__ __launch_bounds__(256)
void attn_kernel(const float* __restrict__ qkv, float* __restrict__ O) {
    int t = blockIdx.x;
    int qt = t % 9; int bh = t / 9; int h = bh % HEADS; int b = bh / HEADS;
    const int tid = threadIdx.x;
    __shared__ float Qs[32][65], Ks[32][65], Vs[32][65], Ps[32][33];
    int q0 = qt * 32;
    for (int e = tid; e < 32 * 64; e += 256) {
        int i = e >> 6, d = e & 63;
        Qs[i][d] = qkv[((size_t)(b * NT + q0 + i)) * 384 + h * 64 + d];
    }
    float m = -INFINITY, l = 0.0f;
    float o[8];
    #pragma unroll
    for (int dd = 0; dd < 8; dd++) o[dd] = 0.0f;
    const int i = tid >> 3;     // query row 0..31
    const int jg = tid & 7;     // j / d group

    for (int kt = 0; kt < 9; kt++) {
        __syncthreads();
        int k0 = kt * 32;
        for (int e = tid; e < 32 * 64; e += 256) {
            int r = e >> 6, d = e & 63;
            size_t rowb = ((size_t)(b * NT + k0 + r)) * 384;
            Ks[r][d] = qkv[rowb + 128 + h * 64 + d];
            Vs[r][d] = qkv[rowb + 256 + h * 64 + d];
        }
        __syncthreads();
        float s[4] = {0.f, 0.f, 0.f, 0.f};
        for (int d = 0; d < 64; d++) {
            float qd = Qs[i][d];
            #pragma unroll
            for (int jj = 0; jj < 4; jj++) s[jj] = fmaf(qd, Ks[jg * 4 + jj][d], s[jj]);
        }
        #pragma unroll
        for (int jj = 0; jj < 4; jj++) s[jj] *= SCALE_;
        float tmax = fmaxf(fmaxf(s[0], s[1]), fmaxf(s[2], s[3]));
        #pragma unroll
        for (int off = 1; off < 8; off <<= 1) tmax = fmaxf(tmax, __shfl_xor(tmax, off));
        float mnew = fmaxf(m, tmax);
        float p[4], ps = 0.0f;
        #pragma unroll
        for (int jj = 0; jj < 4; jj++) { p[jj] = expf(s[jj] - mnew); ps += p[jj]; }
        #pragma unroll
        for (int off = 1; off < 8; off <<= 1) ps += __shfl_xor(ps, off);
        float alpha = expf(m - mnew);
        l = l * alpha + ps;
        m = mnew;
        #pragma unroll
        for (int dd = 0; dd < 8; dd++) o[dd] *= alpha;
        #pragma unroll
        for (int jj = 0; jj < 4; jj++) Ps[i][jg * 4 + jj] = p[jj];
        __syncthreads();
        for (int j = 0; j < 32; j++) {
            float pj = Ps[i][j];
            #pragma unroll
            for (int dd = 0; dd < 8; dd++) o[dd] = fmaf(pj, Vs[j][jg * 8 + dd], o[dd]);
        }
    }
    float rl = 1.0f / l;
    #pragma unroll
    for (int dd = 0; dd < 8; dd++)
        O[((size_t)(b * NT + q0 + i)) * 128 + h * 64 + jg * 8 + dd] = o[dd] * rl;
}

// ---------------- permute g (hp,wp) -> (wp,hp) ----------------
__global__ __launch_bounds__(192)
void permute_g(const float* __restrict__ G, float* __restrict__ G2) {
    int row = blockIdx.x;                    // b*288 + t2 (t2 = wp*16+hp)
    int t2 = row % NT; int b = row / NT;
    int wp = t2 >> 4, hp = t2 & 15;
    int t1 = hp * 18 + wp;
    const float4* src = (const float4*)&G[((size_t)b * NT + t1) * 768];
    float4* dst = (float4*)&G2[(size_t)row * 768];
    dst[threadIdx.x] = src[threadIdx.x];     // 192 float4 = 768 floats
}

// ---------------- dots + argmax (one block per (b, side_i)) ----------------
__global__ __launch_bounds__(256)
void dots_argmax(const float* __restrict__ G2, int* __restrict__ idx) {
    int b = blockIdx.x >> 5, si = blockIdx.x & 31;
    int srow = (si < 16) ? si : (272 + (si - 16));
    const float* S = &G2[((size_t)b * NT + srow) * 768];
    const float* Cb = &G2[((size_t)b * NT + 16) * 768];
    __shared__ float Sv[768];
    __shared__ float red[4];
    __shared__ float vbuf[256];
    __shared__ int ibuf[256];
    int tid = threadIdx.x;
    for (int e = tid; e < 768; e += 256) Sv[e] = S[e];
    __syncthreads();
    float sn = 0.0f;
    for (int e = tid; e < 768; e += 256) sn += Sv[e] * Sv[e];
    float ns = fmaxf(sqrtf(block_sum_1024(sn, red)), 1e-12f);
    const float* cj = &Cb[(size_t)tid * 768];
    float dot = 0.0f, n2 = 0.0f;
    for (int d = 0; d < 768; d += 4) {
        float4 c4 = *(const float4*)&cj[d];
        dot += Sv[d] * c4.x + Sv[d + 1] * c4.y + Sv[d + 2] * c4.z + Sv[d + 3] * c4.w;
        n2  += c4.x * c4.x + c4.y * c4.y + c4.z * c4.z + c4.w * c4.w;
    }
    float val = dot / (fmaxf(sqrtf(n2), 1e-12f) * ns);
    vbuf[tid] = val; ibuf[tid] = tid;
    __syncthreads();
    for (int sft = 128; sft; sft >>= 1) {
        if (tid < sft) {
            float v2 = vbuf[tid + sft]; int i2 = ibuf[tid + sft];
            if (v2 > vbuf[tid] || (v2 == vbuf[tid] && i2 < ibuf[tid])) {
                vbuf[tid] = v2; ibuf[tid] = i2;
            }
        }
        __syncthreads();
    }
    if (tid == 0) idx[blockIdx.x] = ibuf[0];
}

// ---------------- final output assembly ----------------
__global__ __launch_bounds__(256)
void out_assemble(const float* __restrict__ G2, const int* __restrict__ idx,
                  float* __restrict__ out) {
    size_t e = (size_t)blockIdx.x * 256 + threadIdx.x;   // 64*3*256*288
    int ww = (int)(e % 288); size_t r = e / 288;
    int hh = (int)(r % 256); r /= 256;
    int ch = (int)(r % 3); int b = (int)(r / 3);
    int wp = ww >> 4, px = ww & 15, hp = hh >> 4, py = hh & 15;
    int t = wp * 16 + hp;
    int srow;
    if (t < 16)       srow = 16 + idx[b * 32 + t];
    else if (t < 272) srow = t;
    else              srow = 16 + idx[b * 32 + 16 + (t - 272)];
    out[e] = G2[((size_t)b * NT + srow) * 768 + (py * 16 + px) * 3 + ch];
}

// ---------------- host launcher ----------------
extern "C" void kernel_launch(void* const* d_in, const int* in_sizes, int n_in,
                              void* d_out, int out_size, void* d_ws, size_t ws_size,
                              hipStream_t stream) {
    const float* img    = (const float*)d_in[0];
    const float* W_pe   = (const float*)d_in[1];
    const float* b_pe   = (const float*)d_in[2];
    const float* cls_l  = (const float*)d_in[3];
    const float* cls_r  = (const float*)d_in[4];
    const float* W_lin  = (const float*)d_in[5];
    const float* b_lin  = (const float*)d_in[6];
    const float* pos    = (const float*)d_in[7];
    const float* ln1_s  = (const float*)d_in[8];
    const float* ln1_b  = (const float*)d_in[9];
    const float* Wqkv   = (const float*)d_in[10];
    const float* Wo     = (const float*)d_in[11];
    const float* bo     = (const float*)d_in[12];
    const float* ln2_s  = (const float*)d_in[13];
    const float* ln2_b  = (const float*)d_in[14];
    const float* W1     = (const float*)d_in[15];
    const float* b1     = (const float*)d_in[16];
    const float* W2     = (const float*)d_in[17];
    const float* b2     = (const float*)d_in[18];
    const float* lng_s  = (const float*)d_in[19];
    const float* lng_b  = (const float*)d_in[20];
    const float* Wg     = (const float*)d_in[21];
    const float* bg     = (const float*)d_in[22];

    float* ws = (float*)d_ws;
    const size_t X_OFF = 0;                        // B*NT*D = 18,874,368
    const size_t Y_OFF = 18874368;                 // 18,874,368
    const size_t Q_OFF = 37748736;                 // qkv 7,077,888 (g spans 14,155,776)
    const size_t O_OFF = Q_OFF + 7077888;          // o 2,359,296
    const size_t H_OFF = O_OFF + 2359296;          // h 4,718,592
    const size_t AUX   = Q_OFF + 14155776;         // clbuf 32*1024
    const size_t IDXO  = AUX + 32768;              // idx: B*32 ints

    float* x    = ws + X_OFF;
    float* y    = ws + Y_OFF;
    float* qkvb = ws + Q_OFF;
    float* ob   = ws + O_OFF;
    float* hb   = ws + H_OFF;
    float* clb  = ws + AUX;
    int*   idxb = (int*)(ws + IDXO);

    // ---- embed ----
    float* Xp = qkvb;     // patch matrix (B*256, 768) — Q region (dead now)
    float* pe_out = y;    // (B*256, 1024) — Y region
    build_patches<<<49152, 256, 0, stream>>>(img, Xp);
    gemm_f32<1><<<dim3(16, 128), 256, 0, stream>>>(Xp, W_pe, b_pe, pe_out, 16384, 1024, 768);
    gemm_f32<1><<<dim3(16, 1), 256, 0, stream>>>(cls_l, W_lin, b_lin, clb, 16, 1024, 768);
    gemm_f32<1><<<dim3(16, 1), 256, 0, stream>>>(cls_r, W_lin, b_lin, clb + 16 * 1024, 16, 1024, 768);
    assemble_x<<<73728, 256, 0, stream>>>(pe_out, clb, pos, x);

    // ---- transformer layers ----
    const int M = BB * NT;   // 18432
    for (int i = 0; i < DEPTH; i++) {
        ln_kernel<<<M, 256, 0, stream>>>(x, ln1_s + i * 1024, ln1_b + i * 1024, y);
        gemm_f32<0><<<dim3(6, 144), 256, 0, stream>>>(y, Wqkv + (size_t)i * 1024 * 384, nullptr, qkvb, M, 384, 1024);
        attn_kernel<<<BB * HEADS * 9, 256, 0, stream>>>(qkvb, ob);
        gemm_f32<2><<<dim3(16, 144), 256, 0, stream>>>(ob, Wo + (size_t)i * 128 * 1024, bo + i * 1024, x, M, 1024, 128);
        ln_kernel<<<M, 256, 0, stream>>>(x, ln2_s + i * 1024, ln2_b + i * 1024, y);
        gemm_f32<3><<<dim3(4, 144), 256, 0, stream>>>(y, W1 + (size_t)i * 1024 * 256, b1 + i * 256, hb, M, 256, 1024);
        gemm_f32<2><<<dim3(16, 144), 256, 0, stream>>>(hb, W2 + (size_t)i * 256 * 1024, b2 + i * 1024, x, M, 1024, 256);
    }

    // ---- head ----
    ln_kernel<<<M, 256, 0, stream>>>(x, lng_s, lng_b, y);
    float* g = qkvb;                       // (B, 288, 768) — spans qkv+o+h exactly
    gemm_f32<1><<<dim3(12, 144), 256, 0, stream>>>(y, Wg, bg, g, M, 768, 1024);
    float* g2 = x;                         // x dead now
    permute_g<<<BB * NT, 192, 0, stream>>>(g, g2);
    dots_argmax<<<BB * 32, 256, 0, stream>>>(g2, idxb);
    out_assemble<<<55296, 256, 0, stream>>>(g2, idxb, (float*)d_out);
}

// Round 2
// 5902.944 us; speedup vs baseline: 1.5671x; 1.5671x over previous
//
#include <hip/hip_runtime.h>
#include <hip/hip_bf16.h>
#include <math.h>

// ---------------- problem constants ----------------
#define BB 64
#define CC 3
#define HH 256
#define WW 256
#define PP 16
#define DD 1024
#define DEPTH 10
#define HEADS 2
#define DHD 64
#define MLPD 256
#define INNER 128          // HEADS*DHD
#define NCLS 16
#define NT 288             // tokens: 16 cls + 256 patch + 16 cls
#define PDIM 768           // C*P*P
#define SIDE_ 16
#define HPn 16
#define WPn 18
#define SCALE_ 0.125f

typedef unsigned short u16;
typedef __attribute__((ext_vector_type(4))) int   i32x4;
typedef __attribute__((ext_vector_type(4))) float f32x4;

// ---------------- helpers ----------------
__device__ __forceinline__ float gelu_f(float x) {
    return 0.5f * x * (1.0f + erff(x * 0.70710678118654752f));
}

__device__ __forceinline__ u16 f2bf_rne(float x) {
    unsigned u = __float_as_uint(x);
    unsigned r = u + 0x7FFFu + ((u >> 16) & 1u);
    return (u16)(r >> 16);
}
__device__ __forceinline__ void split_bf(float x, u16& h, u16& l) {
    h = f2bf_rne(x);
    float fh = __uint_as_float(((unsigned)h) << 16);
    l = f2bf_rne(x - fh);
}

__device__ __forceinline__ void mfma_bf16(f32x4& acc, i32x4 a, i32x4 b) {
    // D = A*B + C, 16x16x32 bf16. inline asm: avoids builtin type-signature risk.
    asm("v_mfma_f32_16x16x32_bf16 %0, %1, %2, %0" : "+v"(acc) : "v"(a), "v"(b));
}

__device__ __forceinline__ void gload16(const void* g, void* l) {
    __builtin_amdgcn_global_load_lds(
        (const __attribute__((address_space(1))) void*)g,
        (__attribute__((address_space(3))) void*)l, 16, 0, 0);
}

__device__ __forceinline__ float block_sum_1024(float v, float* red) {
    #pragma unroll
    for (int off = 32; off; off >>= 1) v += __shfl_xor(v, off);
    __syncthreads();
    if ((threadIdx.x & 63) == 0) red[threadIdx.x >> 6] = v;
    __syncthreads();
    return red[0] + red[1] + red[2] + red[3];
}

// ---------------- weight convert: W f32 [K][N] -> Wt hi/lo bf16 [N][K] -----
__global__ __launch_bounds__(256)
void convert_wT(const float* __restrict__ W, u16* __restrict__ Wh,
                u16* __restrict__ Wl, int K, int N) {
    __shared__ float t[32][33];
    int n0 = blockIdx.x * 32, k0 = blockIdx.y * 32;
    int c = threadIdx.x & 31, r8 = threadIdx.x >> 5;
    #pragma unroll
    for (int rr = r8; rr < 32; rr += 8)
        t[rr][c] = W[(size_t)(k0 + rr) * N + n0 + c];
    __syncthreads();
    #pragma unroll
    for (int rr = r8; rr < 32; rr += 8) {
        float v = t[c][rr];                 // = W[k0+c][n0+rr]
        u16 h, l; split_bf(v, h, l);
        size_t o = (size_t)(n0 + rr) * K + k0 + c;
        Wh[o] = h; Wl[o] = l;
    }
}

// ---------------- patch gather (split bf16 hi/lo) ----------------
__global__ __launch_bounds__(256)
void build_patches(const float* __restrict__ img, u16* __restrict__ Xh,
                   u16* __restrict__ Xl) {
    size_t e = (size_t)blockIdx.x * 256 + threadIdx.x;  // 64*256*768
    int pd = (int)(e % 768); size_t r = e / 768;
    int t  = (int)(r % 256); int b = (int)(r / 256);
    int c = pd % 3; int pp = pd / 3; int px = pp & 15, py = pp >> 4;
    int wp = t & 15, hp = t >> 4;
    float v = img[(((size_t)b * 3 + c) * 256 + hp * 16 + py) * 256 + wp * 16 + px];
    u16 h, l; split_bf(v, h, l);
    Xh[e] = h; Xl[e] = l;
}

// ---------------- finish embed: add pos, fill cls rows ----------------
__global__ __launch_bounds__(256)
void finish_embed(const float* __restrict__ clb, const float* __restrict__ pos,
                  float* __restrict__ X) {
    size_t e = (size_t)blockIdx.x * 256 + threadIdx.x;   // 64*288*1024
    int d = (int)(e & 1023); size_t r = e >> 10;
    int t = (int)(r % NT);
    float p = pos[t * 1024 + d];
    if (t < 16)        X[e] = clb[t * 1024 + d] + p;
    else if (t >= 272) X[e] = clb[(t - 256) * 1024 + d] + p;
    else               X[e] += p;
}

// ---------------- LayerNorm -> bf16 hi/lo ----------------
__global__ __launch_bounds__(256)
void ln_kernel(const float* __restrict__ X, const float* __restrict__ sc,
               const float* __restrict__ bi, u16* __restrict__ Yh,
               u16* __restrict__ Yl) {
    __shared__ float red[4];
    size_t base = (size_t)blockIdx.x * 1024;
    int tid = threadIdx.x;
    float4 v = *(const float4*)&X[base + tid * 4];
    float s = v.x + v.y + v.z + v.w;
    float mean = block_sum_1024(s, red) * (1.0f / 1024.0f);
    float dx = v.x - mean, dy = v.y - mean, dz = v.z - mean, dw = v.w - mean;
    float sq = dx * dx + dy * dy + dz * dz + dw * dw;
    float var = block_sum_1024(sq, red) * (1.0f / 1024.0f);
    float rs = rsqrtf(var + 1e-5f);
    float4 s4 = *(const float4*)&sc[tid * 4];
    float4 b4 = *(const float4*)&bi[tid * 4];
    float o0 = dx * rs * s4.x + b4.x;
    float o1 = dy * rs * s4.y + b4.y;
    float o2 = dz * rs * s4.z + b4.z;
    float o3 = dw * rs * s4.w + b4.w;
    ushort4 hv, lv;
    split_bf(o0, hv.x, lv.x); split_bf(o1, hv.y, lv.y);
    split_bf(o2, hv.z, lv.z); split_bf(o3, hv.w, lv.w);
    *(ushort4*)&Yh[base + tid * 4] = hv;
    *(ushort4*)&Yl[base + tid * 4] = lv;
}

// ---------------- bf16x3 MFMA GEMM ----------------
// C[M,Nn] = A[M,K] @ W[K,Nn], A given as hi/lo bf16 row-major [M][K],
// W given as hi/lo bf16 TRANSPOSED [Nn][K]. BM=BN=128, BK=32, 4 waves.
// EPI: 0=none,1=+bias,2=+bias+residual(in-place),3=gelu(.+bias)->bf16 hi/lo
// ROWMAP (embed): out row' = row + 16 + 32*(row>>8)
#define SOFF(reg, tile) (((reg) * 8 + (tile)) * 512)
template<int EPI, bool ROWMAP>
__global__ __launch_bounds__(256, 2)
void gemm_bf16x3(const u16* __restrict__ Ah, const u16* __restrict__ Al,
                 const u16* __restrict__ Bh, const u16* __restrict__ Bl,
                 const float* __restrict__ bias, float* __restrict__ out,
                 u16* __restrict__ outH, u16* __restrict__ outL,
                 int M, int Nn, int K) {
    __shared__ u16 smem[32768];           // 2 bufs x (Ah,Al,Bh,Bl) x 8 tiles x 1KB
    const int tid = threadIdx.x;
    const int w = tid >> 6, lane = tid & 63;
    const int wr = w >> 1, wc = w & 1;
    const int m0 = blockIdx.y << 7, n0 = blockIdx.x << 7;
    const int lr = lane & 15, lg = lane >> 4;

    // staging: wave w loads A tiles {2w,2w+1} and B tiles {2w,2w+1}, hi+lo
    const u16* gp[8];
    int lb[8];
    {
        size_t a0 = (size_t)(m0 + (2 * w) * 16 + lr) * K + lg * 8;
        size_t a1 = (size_t)(m0 + (2 * w + 1) * 16 + lr) * K + lg * 8;
        size_t b0 = (size_t)(n0 + (2 * w) * 16 + lr) * K + lg * 8;
        size_t b1 = (size_t)(n0 + (2 * w + 1) * 16 + lr) * K + lg * 8;
        gp[0] = Ah + a0; gp[1] = Ah + a1; gp[2] = Al + a0; gp[3] = Al + a1;
        gp[4] = Bh + b0; gp[5] = Bh + b1; gp[6] = Bl + b0; gp[7] = Bl + b1;
        lb[0] = SOFF(0, 2 * w); lb[1] = SOFF(0, 2 * w + 1);
        lb[2] = SOFF(1, 2 * w); lb[3] = SOFF(1, 2 * w + 1);
        lb[4] = SOFF(2, 2 * w); lb[5] = SOFF(2, 2 * w + 1);
        lb[6] = SOFF(3, 2 * w); lb[7] = SOFF(3, 2 * w + 1);
    }

    f32x4 acc[4][4];
    #pragma unroll
    for (int i = 0; i < 4; i++)
        #pragma unroll
        for (int j = 0; j < 4; j++) acc[i][j] = f32x4{0.f, 0.f, 0.f, 0.f};

    // prologue: stage k-step 0 into buf 0
    #pragma unroll
    for (int q = 0; q < 8; q++) { gload16(gp[q], &smem[lb[q]]); gp[q] += 32; }
    __syncthreads();

    const int nks = K >> 5;
    const int lo8 = lane * 8;
    for (int ks = 0; ks < nks; ks++) {
        const int bb = (ks & 1) << 14;
        if (ks + 1 < nks) {
            const int nb = bb ^ 16384;
            #pragma unroll
            for (int q = 0; q < 8; q++) { gload16(gp[q], &smem[lb[q] + nb]); gp[q] += 32; }
        }
        i32x4 a_h[4], a_l[4], b_h[4], b_l[4];
        #pragma unroll
        for (int i = 0; i < 4; i++) {
            a_h[i] = *(const i32x4*)&smem[bb + SOFF(0, wr * 4 + i) + lo8];
            a_l[i] = *(const i32x4*)&smem[bb + SOFF(1, wr * 4 + i) + lo8];
            b_h[i] = *(const i32x4*)&smem[bb + SOFF(2, wc * 4 + i) + lo8];
            b_l[i] = *(const i32x4*)&smem[bb + SOFF(3, wc * 4 + i) + lo8];
        }
        #pragma unroll
        for (int i = 0; i < 4; i++)
            #pragma unroll
            for (int j = 0; j < 4; j++) {
                mfma_bf16(acc[i][j], a_h[i], b_h[j]);
                mfma_bf16(acc[i][j], a_h[i], b_l[j]);
                mfma_bf16(acc[i][j], a_l[i], b_h[j]);
            }
        __syncthreads();
    }

    // epilogue: D[row=(lane>>4)*4+reg][col=lane&15] per 16x16 fragment
    #pragma unroll
    for (int j = 0; j < 4; j++) {
        const int col = n0 + (wc * 4 + j) * 16 + lr;
        float bv = (EPI >= 1) ? bias[col] : 0.0f;
        #pragma unroll
        for (int i = 0; i < 4; i++) {
            const int rowb = m0 + (wr * 4 + i) * 16 + lg * 4;
            #pragma unroll
            for (int r = 0; r < 4; r++) {
                int row = rowb + r;
                int orow = ROWMAP ? (row + 16 + 32 * (row >> 8)) : row;
                size_t oidx = (size_t)orow * Nn + col;
                float v = acc[i][j][r] + bv;
                if (EPI == 3) {
                    float g = gelu_f(v);
                    u16 h, l; split_bf(g, h, l);
                    outH[oidx] = h; outL[oidx] = l;
                } else if (EPI == 2) {
                    out[oidx] = v + out[oidx];
                } else {
                    out[oidx] = v;
                }
            }
        }
    }
}

// ---------------- f32 GEMM (kept only for tiny cls matmuls, M=16) ----------
template<int EPI>
__global__ __launch_bounds__(256)
void gemm_f32(const float* __restrict__ A, const float* __restrict__ Wt,
              const float* __restrict__ bias, float* __restrict__ Cout,
              int M, int Nn, int K) {
    __shared__ float As[16][132];
    __shared__ float Bs[16][68];
    const int tid = threadIdx.x;
    const int m0 = blockIdx.y * 128;
    const int n0 = blockIdx.x * 64;
    const int ty = tid >> 4, tx = tid & 15;
    float acc[8][4];
    #pragma unroll
    for (int r = 0; r < 8; r++)
        #pragma unroll
        for (int c = 0; c < 4; c++) acc[r][c] = 0.0f;
    const int af4 = tid & 3;
    const int arow0 = tid >> 2;
    const int bcol = tid & 63, brow0 = tid >> 6;
    for (int k0 = 0; k0 < K; k0 += 16) {
        #pragma unroll
        for (int rr = 0; rr < 2; rr++) {
            int row = arow0 + rr * 64;
            int gm = m0 + row;
            float4 v = make_float4(0.f, 0.f, 0.f, 0.f);
            if (gm < M) v = *(const float4*)&A[(size_t)gm * K + k0 + af4 * 4];
            As[af4 * 4 + 0][row] = v.x; As[af4 * 4 + 1][row] = v.y;
            As[af4 * 4 + 2][row] = v.z; As[af4 * 4 + 3][row] = v.w;
        }
        #pragma unroll
        for (int rr = 0; rr < 4; rr++) {
            int krow = brow0 + rr * 4;
            Bs[krow][bcol] = Wt[(size_t)(k0 + krow) * Nn + n0 + bcol];
        }
        __syncthreads();
        #pragma unroll
        for (int kk = 0; kk < 16; kk++) {
            float4 a0 = *(const float4*)&As[kk][ty * 8];
            float4 a1 = *(const float4*)&As[kk][ty * 8 + 4];
            float4 b0 = *(const float4*)&Bs[kk][tx * 4];
            float ar[8] = {a0.x, a0.y, a0.z, a0.w, a1.x, a1.y, a1.z, a1.w};
            float bc[4] = {b0.x, b0.y, b0.z, b0.w};
            #pragma unroll
            for (int r = 0; r < 8; r++)
                #pragma unroll
                for (int c = 0; c < 4; c++)
                    acc[r][c] = fmaf(ar[r], bc[c], acc[r][c]);
        }
        __syncthreads();
    }
    float4 bv = make_float4(0.f, 0.f, 0.f, 0.f);
    if (EPI >= 1) bv = *(const float4*)&bias[n0 + tx * 4];
    #pragma unroll
    for (int r = 0; r < 8; r++) {
        int gm = m0 + ty * 8 + r;
        if (gm >= M) continue;
        float4 v = make_float4(acc[r][0], acc[r][1], acc[r][2], acc[r][3]);
        if (EPI >= 1) { v.x += bv.x; v.y += bv.y; v.z += bv.z; v.w += bv.w; }
        *(float4*)&Cout[(size_t)gm * Nn + n0 + tx * 4] = v;
    }
}

// ---------------- attention (flash-style, f32) -> bf16 hi/lo O ----------
__global__ __launch_bounds__(256)
void attn_kernel(const float* __restrict__ qkv, u16* __restrict__ Oh,
                 u16* __restrict__ Ol) {
    int t = blockIdx.x;
    int qt = t % 9; int bh = t / 9; int h = bh % HEADS; int b = bh / HEADS;
    const int tid = threadIdx.x;
    __shared__ float Qs[32][65], Ks[32][65], Vs[32][65], Ps[32][33];
    int q0 = qt * 32;
    for (int e = tid; e < 32 * 64; e += 256) {
        int i = e >> 6, d = e & 63;
        Qs[i][d] = qkv[((size_t)(b * NT + q0 + i)) * 384 + h * 64 + d];
    }
    float m = -INFINITY, l = 0.0f;
    float o[8];
    #pragma unroll
    for (int dd = 0; dd < 8; dd++) o[dd] = 0.0f;
    const int i = tid >> 3;
    const int jg = tid & 7;
    for (int kt = 0; kt < 9; kt++) {
        __syncthreads();
        int k0 = kt * 32;
        for (int e = tid; e < 32 * 64; e += 256) {
            int r = e >> 6, d = e & 63;
            size_t rowb = ((size_t)(b * NT + k0 + r)) * 384;
            Ks[r][d] = qkv[rowb + 128 + h * 64 + d];
            Vs[r][d] = qkv[rowb + 256 + h * 64 + d];
        }
        __syncthreads();
        float s[4] = {0.f, 0.f, 0.f, 0.f};
        for (int d = 0; d < 64; d++) {
            float qd = Qs[i][d];
            #pragma unroll
            for (int jj = 0; jj < 4; jj++) s[jj] = fmaf(qd, Ks[jg * 4 + jj][d], s[jj]);
        }
        #pragma unroll
        for (int jj = 0; jj < 4; jj++) s[jj] *= SCALE_;
        float tmax = fmaxf(fmaxf(s[0], s[1]), fmaxf(s[2], s[3]));
        #pragma unroll
        for (int off = 1; off < 8; off <<= 1) tmax = fmaxf(tmax, __shfl_xor(tmax, off));
        float mnew = fmaxf(m, tmax);
        float p[4], ps = 0.0f;
        #pragma unroll
        for (int jj = 0; jj < 4; jj++) { p[jj] = expf(s[jj] - mnew); ps += p[jj]; }
        #pragma unroll
        for (int off = 1; off < 8; off <<= 1) ps += __shfl_xor(ps, off);
        float alpha = expf(m - mnew);
        l = l * alpha + ps;
        m = mnew;
        #pragma unroll
        for (int dd = 0; dd < 8; dd++) o[dd] *= alpha;
        #pragma unroll
        for (int jj = 0; jj < 4; jj++) Ps[i][jg * 4 + jj] = p[jj];
        __syncthreads();
        for (int j = 0; j < 32; j++) {
            float pj = Ps[i][j];
            #pragma unroll
            for (int dd = 0; dd < 8; dd++) o[dd] = fmaf(pj, Vs[j][jg * 8 + dd], o[dd]);
        }
    }
    float rl = 1.0f / l;
    #pragma unroll
    for (int dd = 0; dd < 8; dd++) {
        float v = o[dd] * rl;
        u16 hh, ll; split_bf(v, hh, ll);
        size_t oidx = ((size_t)(b * NT + q0 + i)) * 128 + h * 64 + jg * 8 + dd;
        Oh[oidx] = hh; Ol[oidx] = ll;
    }
}

// ---------------- permute g (hp,wp) -> (wp,hp) ----------------
__global__ __launch_bounds__(192)
void permute_g(const float* __restrict__ G, float* __restrict__ G2) {
    int row = blockIdx.x;
    int t2 = row % NT; int b = row / NT;
    int wp = t2 >> 4, hp = t2 & 15;
    int t1 = hp * 18 + wp;
    const float4* src = (const float4*)&G[((size_t)b * NT + t1) * 768];
    float4* dst = (float4*)&G2[(size_t)row * 768];
    dst[threadIdx.x] = src[threadIdx.x];
}

// ---------------- dots + argmax ----------------
__global__ __launch_bounds__(256)
void dots_argmax(const float* __restrict__ G2, int* __restrict__ idx) {
    int b = blockIdx.x >> 5, si = blockIdx.x & 31;
    int srow = (si < 16) ? si : (272 + (si - 16));
    const float* S = &G2[((size_t)b * NT + srow) * 768];
    const float* Cb = &G2[((size_t)b * NT + 16) * 768];
    __shared__ float Sv[768];
    __shared__ float red[4];
    __shared__ float vbuf[256];
    __shared__ int ibuf[256];
    int tid = threadIdx.x;
    for (int e = tid; e < 768; e += 256) Sv[e] = S[e];
    __syncthreads();
    float sn = 0.0f;
    for (int e = tid; e < 768; e += 256) sn += Sv[e] * Sv[e];
    float ns = fmaxf(sqrtf(block_sum_1024(sn, red)), 1e-12f);
    const float* cj = &Cb[(size_t)tid * 768];
    float dot = 0.0f, n2 = 0.0f;
    for (int d = 0; d < 768; d += 4) {
        float4 c4 = *(const float4*)&cj[d];
        dot += Sv[d] * c4.x + Sv[d + 1] * c4.y + Sv[d + 2] * c4.z + Sv[d + 3] * c4.w;
        n2  += c4.x * c4.x + c4.y * c4.y + c4.z * c4.z + c4.w * c4.w;
    }
    float val = dot / (fmaxf(sqrtf(n2), 1e-12f) * ns);
    vbuf[tid] = val; ibuf[tid] = tid;
    __syncthreads();
    for (int sft = 128; sft; sft >>= 1) {
        if (tid < sft) {
            float v2 = vbuf[tid + sft]; int i2 = ibuf[tid + sft];
            if (v2 > vbuf[tid] || (v2 == vbuf[tid] && i2 < ibuf[tid])) {
                vbuf[tid] = v2; ibuf[tid] = i2;
            }
        }
        __syncthreads();
    }
    if (tid == 0) idx[blockIdx.x] = ibuf[0];
}

// ---------------- final output assembly ----------------
__global__ __launch_bounds__(256)
void out_assemble(const float* __restrict__ G2, const int* __restrict__ idx,
                  float* __restrict__ out) {
    size_t e = (size_t)blockIdx.x * 256 + threadIdx.x;
    int ww = (int)(e % 288); size_t r = e / 288;
    int hh = (int)(r % 256); r /= 256;
    int ch = (int)(r % 3); int b = (int)(r / 3);
    int wp = ww >> 4, px = ww & 15, hp = hh >> 4, py = hh & 15;
    int t = wp * 16 + hp;
    int srow;
    if (t < 16)       srow = 16 + idx[b * 32 + t];
    else if (t < 272) srow = t;
    else              srow = 16 + idx[b * 32 + 16 + (t - 272)];
    out[e] = G2[((size_t)b * NT + srow) * 768 + (py * 16 + px) * 3 + ch];
}

// ---------------- host launcher ----------------
extern "C" void kernel_launch(void* const* d_in, const int* in_sizes, int n_in,
                              void* d_out, int out_size, void* d_ws, size_t ws_size,
                              hipStream_t stream) {
    const float* img    = (const float*)d_in[0];
    const float* W_pe   = (const float*)d_in[1];
    const float* b_pe   = (const float*)d_in[2];
    const float* cls_l  = (const float*)d_in[3];
    const float* cls_r  = (const float*)d_in[4];
    const float* W_lin  = (const float*)d_in[5];
    const float* b_lin  = (const float*)d_in[6];
    const float* pos    = (const float*)d_in[7];
    const float* ln1_s  = (const float*)d_in[8];
    const float* ln1_b  = (const float*)d_in[9];
    const float* Wqkv   = (const float*)d_in[10];
    const float* Wo     = (const float*)d_in[11];
    const float* bo     = (const float*)d_in[12];
    const float* ln2_s  = (const float*)d_in[13];
    const float* ln2_b  = (const float*)d_in[14];
    const float* W1     = (const float*)d_in[15];
    const float* b1     = (const float*)d_in[16];
    const float* W2     = (const float*)d_in[17];
    const float* b2     = (const float*)d_in[18];
    const float* lng_s  = (const float*)d_in[19];
    const float* lng_b  = (const float*)d_in[20];
    const float* Wg     = (const float*)d_in[21];
    const float* bg     = (const float*)d_in[22];

    unsigned char* wsb = (unsigned char*)d_ws;
    // byte layout (total 193,077,248 B; round-0 proved >=207MB available)
    float* x   = (float*)(wsb + 0);                       // 75,497,472 B (also g)
    u16*  yh   = (u16*)(wsb + 75497472);                  // B region
    u16*  yl   = (u16*)(wsb + 113246208);
    u16*  xph  = (u16*)(wsb + 75497472);                  // embed-phase alias
    u16*  xpl  = (u16*)(wsb + 100663296);
    float* g2  = (float*)(wsb + 75497472);                // head-phase alias
    float* qkvb = (float*)(wsb + 150994944);              // D region
    u16*  hh   = (u16*)(wsb + 150994944);                 // aliases qkv (dead then)
    u16*  hl   = (u16*)(wsb + 160432128);
    u16*  oh   = (u16*)(wsb + 179306496);
    u16*  ol   = (u16*)(wsb + 184025088);
    u16*  wQh  = (u16*)(wsb + 188743680);
    u16*  wQl  = (u16*)(wsb + 189530112);
    u16*  wOh  = (u16*)(wsb + 190316544);
    u16*  wOl  = (u16*)(wsb + 190578688);
    u16*  w1h  = (u16*)(wsb + 190840832);
    u16*  w1l  = (u16*)(wsb + 191365120);
    u16*  w2h  = (u16*)(wsb + 191889408);
    u16*  w2l  = (u16*)(wsb + 192413696);
    u16*  wEh  = (u16*)(wsb + 188743680);                 // embed/head slot (1.57MB each)
    u16*  wEl  = (u16*)(wsb + 190316544);
    float* clb = (float*)(wsb + 192937984);
    int*  idxb = (int*)(wsb + 193069056);
    float* g   = x;

    // ---- embed ----
    convert_wT<<<dim3(32, 24), 256, 0, stream>>>(W_pe, wEh, wEl, 768, 1024);
    build_patches<<<49152, 256, 0, stream>>>(img, xph, xpl);
    gemm_bf16x3<1, true><<<dim3(8, 128), 256, 0, stream>>>(
        xph, xpl, wEh, wEl, b_pe, x, nullptr, nullptr, 16384, 1024, 768);
    gemm_f32<1><<<dim3(16, 1), 256, 0, stream>>>(cls_l, W_lin, b_lin, clb, 16, 1024, 768);
    gemm_f32<1><<<dim3(16, 1), 256, 0, stream>>>(cls_r, W_lin, b_lin, clb + 16 * 1024, 16, 1024, 768);
    finish_embed<<<73728, 256, 0, stream>>>(clb, pos, x);

    // ---- transformer layers ----
    const int M = BB * NT;   // 18432
    for (int i = 0; i < DEPTH; i++) {
        convert_wT<<<dim3(12, 32), 256, 0, stream>>>(Wqkv + (size_t)i * 393216, wQh, wQl, 1024, 384);
        convert_wT<<<dim3(32, 4),  256, 0, stream>>>(Wo   + (size_t)i * 131072, wOh, wOl, 128, 1024);
        convert_wT<<<dim3(8, 32),  256, 0, stream>>>(W1   + (size_t)i * 262144, w1h, w1l, 1024, 256);
        convert_wT<<<dim3(32, 8),  256, 0, stream>>>(W2   + (size_t)i * 262144, w2h, w2l, 256, 1024);
        ln_kernel<<<M, 256, 0, stream>>>(x, ln1_s + i * 1024, ln1_b + i * 1024, yh, yl);
        gemm_bf16x3<0, false><<<dim3(3, 144), 256, 0, stream>>>(
            yh, yl, wQh, wQl, nullptr, qkvb, nullptr, nullptr, M, 384, 1024);
        attn_kernel<<<BB * HEADS * 9, 256, 0, stream>>>(qkvb, oh, ol);
        gemm_bf16x3<2, false><<<dim3(8, 144), 256, 0, stream>>>(
            oh, ol, wOh, wOl, bo + i * 1024, x, nullptr, nullptr, M, 1024, 128);
        ln_kernel<<<M, 256, 0, stream>>>(x, ln2_s + i * 1024, ln2_b + i * 1024, yh, yl);
        gemm_bf16x3<3, false><<<dim3(2, 144), 256, 0, stream>>>(
            yh, yl, w1h, w1l, b1 + i * 256, nullptr, hh, hl, M, 256, 1024);
        gemm_bf16x3<2, false><<<dim3(8, 144), 256, 0, stream>>>(
            hh, hl, w2h, w2l, b2 + i * 1024, x, nullptr, nullptr, M, 1024, 256);
    }

    // ---- head ----
    convert_wT<<<dim3(24, 32), 256, 0, stream>>>(Wg, wEh, wEl, 1024, 768);
    ln_kernel<<<M, 256, 0, stream>>>(x, lng_s, lng_b, yh, yl);
    gemm_bf16x3<1, false><<<dim3(6, 144), 256, 0, stream>>>(
        yh, yl, wEh, wEl, bg, g, nullptr, nullptr, M, 768, 1024);
    permute_g<<<BB * NT, 192, 0, stream>>>(g, g2);
    dots_argmax<<<BB * 32, 256, 0, stream>>>(g2, idxb);
    out_assemble<<<55296, 256, 0, stream>>>(g2, idxb, (float*)d_out);
}